// Round 1
// 303.846 us; speedup vs baseline: 1.0896x; 1.0896x over previous
//
#include <hip/hip_runtime.h>

// CRF loss: mean over batch of (logZ - path_score).  B=512, T=1024, K=48.
//
// Forward: 16 sequences per block, 32 blocks x 256 threads (4 waves, one per
// SIMD). wave 0 = consumer (MFMA recurrence), waves 1..3 = producers
// (global->VGPR->exp->LDS ring). Flag handshake in LDS, no __syncthreads in
// the pipeline.
//
// R8 (this round): counters showed ~504 cy/step with only ~35 cy MFMA + ~105
// cy VALU accounted -> ~70% stall = handshake/starvation, not compute.
//  - producers double-buffer L (LA/LB) and issue loads TWO phases ahead;
//    phase loop unrolled x2 so the compiler tracks counted vmcnt(9) and
//    never drains the queue. (old code issued loads 1 poll-gap before use ->
//    exposed full HBM latency every phase in steady state)
//  - __threadfence_block (vmcnt(0)+lgkmcnt(0) drain) replaced by
//    s_waitcnt lgkmcnt(0) + compiler barrier; DS ops are in-order per wave,
//    so flag-after-data needs only lgkm completion.
//  - consumer polls all 3 producer flags with ONE ds_read_b128 (int[4]),
//    tight spin (no s_sleep on the critical wave). Old: 3 short-circuited
//    volatile reads = 3 dependent LDS round trips per phase.
//  - consumer flags cons=k+1 early (top of step 7; its last phase-k reads
//    are register-resident and lgkm-waited) -> producers get the slot gate
//    ~2 steps sooner.
//  - phase loop unrolled x2 (t0 mod 16 alternates 1/9) -> all ring slot
//    offsets are compile-time immediates for ds_read/ds_write.
//  - depth-2 X prefetch inside the phase; f32x4 vector muls (v_pk_mul_f32).
//  - rescale/capture cross-lane reduce via v_permlane16/32_swap (VALU-speed)
//    instead of 2 dependent ds_bpermute shuffles (~260 cy every 8 steps).
//
// Kept from earlier rounds: stride-13 LDS layout (bank-conflict fix, r7),
// pre-exponentiated emissions (r6), explicit X prefetch (r7), 16-slot ring,
// per-column rescale every 8 steps, ballot-guarded logZ capture at t==len-1.
// Path-score blocks (32..543) share the launch and overlap the forward waves.

#define BB    512
#define TT    1024
#define KK    48
#define GG    16
#define NGRP  32
#define NSLOT 16
#define SLOTB (13 * GG * 16)    // 3328 B per time-step slot (stride-13)
#define PHASE 8
#define BLKT  256

typedef __attribute__((ext_vector_type(4))) short bf16x4;
typedef __attribute__((ext_vector_type(4))) float f32x4;
typedef __attribute__((ext_vector_type(4))) int   i32x4;

__device__ __forceinline__ f32x4 mfma16(bf16x4 a, bf16x4 b, f32x4 c) {
#if __has_builtin(__builtin_amdgcn_mfma_f32_16x16x16bf16_1k)
    return __builtin_amdgcn_mfma_f32_16x16x16bf16_1k(a, b, c, 0, 0, 0);
#else
    f32x4 d;
    asm volatile("v_mfma_f32_16x16x16_bf16 %0, %1, %2, %3"
                 : "=v"(d) : "v"(a), "v"(b), "v"(c));
    return d;
#endif
}

#if __has_builtin(__builtin_amdgcn_cvt_pk_bf16_f32)
typedef __attribute__((ext_vector_type(2))) __bf16 bf16x2_v;
__device__ __forceinline__ unsigned pk2(float lo, float hi) {
    union { bf16x2_v v; unsigned u; } x;
    x.v = __builtin_amdgcn_cvt_pk_bf16_f32(lo, hi);
    return x.u;
}
#else
__device__ __forceinline__ unsigned pk2(float lo, float hi) {
    return __builtin_amdgcn_perm(__float_as_uint(hi) + 0x8000u,
                                 __float_as_uint(lo) + 0x8000u,
                                 0x07060302u);
}
#endif
__device__ __forceinline__ bf16x4 pack4(float a, float b, float c, float d) {
    union { unsigned u[2]; bf16x4 v; } x;
    x.u[0] = pk2(a, b);
    x.u[1] = pk2(c, d);
    return x.v;
}

// VALU-speed lane^16 / lane^32 exchange (pair of outputs always covers
// {x[i], x[i^N]} regardless of swap direction). Fallback: ds_bpermute shfl.
#if __has_builtin(__builtin_amdgcn_permlane16_swap)
__device__ __forceinline__ float swap16_max(float x) {
    auto p = __builtin_amdgcn_permlane16_swap(__float_as_int(x),
                                              __float_as_int(x), false, false);
    return fmaxf(__int_as_float(p[0]), __int_as_float(p[1]));
}
__device__ __forceinline__ float swap16_sum(float x) {
    auto p = __builtin_amdgcn_permlane16_swap(__float_as_int(x),
                                              __float_as_int(x), false, false);
    return __int_as_float(p[0]) + __int_as_float(p[1]);
}
#else
__device__ __forceinline__ float swap16_max(float x) { return fmaxf(x, __shfl_xor(x, 16, 64)); }
__device__ __forceinline__ float swap16_sum(float x) { return x + __shfl_xor(x, 16, 64); }
#endif
#if __has_builtin(__builtin_amdgcn_permlane32_swap)
__device__ __forceinline__ float swap32_max(float x) {
    auto p = __builtin_amdgcn_permlane32_swap(__float_as_int(x),
                                              __float_as_int(x), false, false);
    return fmaxf(__int_as_float(p[0]), __int_as_float(p[1]));
}
__device__ __forceinline__ float swap32_sum(float x) {
    auto p = __builtin_amdgcn_permlane32_swap(__float_as_int(x),
                                              __float_as_int(x), false, false);
    return __int_as_float(p[0]) + __int_as_float(p[1]);
}
#else
__device__ __forceinline__ float swap32_max(float x) { return fmaxf(x, __shfl_xor(x, 32, 64)); }
__device__ __forceinline__ float swap32_sum(float x) { return x + __shfl_xor(x, 32, 64); }
#endif

__device__ __forceinline__ float wave_reduce_sum(float v) {
    #pragma unroll
    for (int off = 32; off > 0; off >>= 1)
        v += __shfl_xor(v, off, 64);
    return v;
}

__global__ __launch_bounds__(BLKT, 1) void crf_main_kernel(
    const float* __restrict__ emis,    // [B,T,K]
    const int*   __restrict__ lengths, // [B]
    const int*   __restrict__ tags,    // [B,T]
    const float* __restrict__ prior,   // [K]
    const float* __restrict__ trans,   // [K,K] trans[dest][src]
    const float* __restrict__ finalT,  // [K]
    float*       __restrict__ ws)      // [0..511] logZ, [512..1023] path
{
    __shared__ __align__(16) unsigned char ring[NSLOT * SLOTB];  // 53 KB
    __shared__ __align__(16) int prodCnt4[4];
    __shared__ int consCnt;

    const int tid  = threadIdx.x;
    const int wv   = tid >> 6;
    const int lane = tid & 63;

    // ================= path-score blocks =================
    if (blockIdx.x >= NGRP) {
        const int b = blockIdx.x - NGRP;
        int len = lengths[b];
        len = (len < 1) ? 1 : (len > TT ? TT : len);
        const float* eb = emis + (size_t)b * TT * KK;
        const int*   tg = tags + (size_t)b * TT;
        float ps = 0.0f;
        for (int t = tid; t < len; t += BLKT) {
            int cur = tg[t];
            float ev = eb[(size_t)t * KK + cur];
            float tr = (t == 0) ? prior[cur] : trans[cur * KK + tg[t - 1]];
            ps += ev + tr;
        }
        ps = wave_reduce_sum(ps);
        float* red = (float*)ring;
        if (lane == 0) red[wv] = ps;
        __syncthreads();
        if (tid == 0)
            ws[BB + b] = red[0] + red[1] + red[2] + red[3] + finalT[tg[len - 1]];
        return;
    }

    // ================= forward blocks =================
    const int g = blockIdx.x;
    __builtin_amdgcn_s_setprio(1);   // vs transient co-resident path blocks

    if (tid == 0) {
        prodCnt4[0] = 0; prodCnt4[1] = 0; prodCnt4[2] = 0; prodCnt4[3] = 0;
        consCnt = 0;
    }
    __syncthreads();   // one-time flag init

    // gmax computed identically by every wave
    int myLen = lengths[g * GG + (lane & 15)];
    myLen = (myLen < 1) ? 1 : (myLen > TT ? TT : myLen);
    int gmax = myLen;
    #pragma unroll
    for (int off = 32; off > 0; off >>= 1) {
        int o = __shfl_xor(gmax, off, 64);
        gmax = (o > gmax) ? o : gmax;
    }
    const int nsteps = gmax - 1;                 // steps t = 1..nsteps
    const int nphase = (nsteps + PHASE - 1) / PHASE;

    if (wv >= 1) {
        // ---------------- producer waves (1..3) ----------------
        // linear granule lidx = lane + 64j (j=0..2): seq = lidx/12, kg =
        // lidx%12. Global: seq-major packed (coalesced 192B runs). LDS:
        // stride-13 placement (seq*13+kg)*16.
        const float* gp[3]; int lo[3];
        #pragma unroll
        for (int j = 0; j < 3; ++j) {
            int lidx = lane + 64 * j;
            int s    = lidx / 12;
            int kg   = lidx - s * 12;
            gp[j]    = emis + (size_t)(g * GG + s) * (TT * KK) + kg * 4;
            lo[j]    = (s * 13 + kg) * 16;
        }
        const int sA = wv - 1;       // slots sA, sA+3, sA+6 (skip if >=8)
        float4 LA[9], LB[9];

#define PLOADX(Lb, KP)                                                     \
        {                                                                  \
            _Pragma("unroll")                                              \
            for (int h = 0; h < 3; ++h) {                                  \
                int s = sA + 3 * h;                                        \
                if (s < PHASE) {                                           \
                    int t  = 1 + (KP) * PHASE + s;                         \
                    int tc = (t > nsteps) ? nsteps : t;                    \
                    _Pragma("unroll")                                      \
                    for (int j = 0; j < 3; ++j)                            \
                        Lb[h * 3 + j] = *reinterpret_cast<const float4*>(  \
                            gp[j] + (size_t)tc * KK);                      \
                }                                                          \
            }                                                              \
        }

#define PSTORE(Lb, SB)                                                     \
        {                                                                  \
            _Pragma("unroll")                                              \
            for (int h = 0; h < 3; ++h) {                                  \
                int s = sA + 3 * h;                                        \
                if (s < PHASE) {                                           \
                    unsigned char* bp =                                    \
                        &ring[(((SB) + s) & (NSLOT - 1)) * SLOTB];         \
                    _Pragma("unroll")                                      \
                    for (int j = 0; j < 3; ++j) {                          \
                        float4 l = Lb[h * 3 + j];                          \
                        float4 e;                                          \
                        e.x = __expf(l.x); e.y = __expf(l.y);              \
                        e.z = __expf(l.z); e.w = __expf(l.w);              \
                        *reinterpret_cast<float4*>(bp + lo[j]) = e;        \
                    }                                                      \
                }                                                          \
            }                                                              \
        }

        // two phases of loads in flight before the loop
        PLOADX(LA, 0);
        PLOADX(LB, 1);
        volatile int* vc = &consCnt;
        for (int k0 = 0; k0 < nphase; k0 += 2) {
            // ---- even phase k0: slots (1+s)&15, buffer LA ----
            while (*vc < k0 - 1) __builtin_amdgcn_s_sleep(1);  // slot reuse gate
            asm volatile("" ::: "memory");
            PSTORE(LA, 1);
            asm volatile("s_waitcnt lgkmcnt(0)" ::: "memory"); // data committed
            if (lane == 0) *(volatile int*)&prodCnt4[sA] = k0 + 1;
            asm volatile("" ::: "memory");
            PLOADX(LA, k0 + 2);                  // 2 phases ahead, in flight
            // ---- odd phase k0+1: slots (9+s)&15, buffer LB ----
            if (k0 + 1 < nphase) {
                while (*vc < k0) __builtin_amdgcn_s_sleep(1);
                asm volatile("" ::: "memory");
                PSTORE(LB, 9);
                asm volatile("s_waitcnt lgkmcnt(0)" ::: "memory");
                if (lane == 0) *(volatile int*)&prodCnt4[sA] = k0 + 2;
                asm volatile("" ::: "memory");
                PLOADX(LB, k0 + 3);
            }
        }
#undef PLOADX
#undef PSTORE
        return;
    }

    // ---------------- consumer (MFMA) wave ----------------
    const int col   = lane & 15;
    const int grp   = lane >> 4;
    const int rbase = grp * 4;
    const int seq   = g * GG + col;
    const int lenn1 = myLen - 1;

    // A tiles: bf16(exp(trans)); A[m][k]: m = mt*16+col, k = kt*16+rbase+j
    bf16x4 A[3][3];
    #pragma unroll
    for (int mt = 0; mt < 3; ++mt) {
        #pragma unroll
        for (int kt = 0; kt < 3; ++kt) {
            float4 tv = *reinterpret_cast<const float4*>(
                trans + (size_t)(mt * 16 + col) * KK + kt * 16 + rbase);
            A[mt][kt] = pack4(__expf(tv.x), __expf(tv.y),
                              __expf(tv.z), __expf(tv.w));
        }
    }

    f32x4 EF[3];
    #pragma unroll
    for (int mt = 0; mt < 3; ++mt) {
        float4 fv = *reinterpret_cast<const float4*>(finalT + mt * 16 + rbase);
        EF[mt][0] = __expf(fv.x); EF[mt][1] = __expf(fv.y);
        EF[mt][2] = __expf(fv.z); EF[mt][3] = __expf(fv.w);
    }

    const float* ebase = emis + (size_t)seq * TT * KK + rbase;

    // init (t=0): w = exp(E0 + prior - c), c = per-column max
    float c;
    float zcap = 0.0f;
    bf16x4 Bt0, Bt1, Bt2;
    {
        f32x4 a0[3];
        #pragma unroll
        for (int mt = 0; mt < 3; ++mt) {
            f32x4 ev = *reinterpret_cast<const f32x4*>(ebase + mt * 16);
            f32x4 pv = *reinterpret_cast<const f32x4*>(prior + mt * 16 + rbase);
            a0[mt] = ev + pv;
        }
        float mx = fmaxf(
            fmaxf(fmaxf(fmaxf(a0[0][0], a0[0][1]), fmaxf(a0[0][2], a0[0][3])),
                  fmaxf(fmaxf(a0[1][0], a0[1][1]), fmaxf(a0[1][2], a0[1][3]))),
            fmaxf(fmaxf(a0[2][0], a0[2][1]), fmaxf(a0[2][2], a0[2][3])));
        mx = swap16_max(mx);
        mx = swap32_max(mx);
        c = mx;
        #pragma unroll
        for (int mt = 0; mt < 3; ++mt) {
            #pragma unroll
            for (int e = 0; e < 4; ++e) a0[mt][e] = __expf(a0[mt][e] - c);
        }
        if (__ballot(lenn1 == 0)) {
            f32x4 Sv = a0[0] * EF[0] + a0[1] * EF[1] + a0[2] * EF[2];
            float S = (Sv[0] + Sv[1]) + (Sv[2] + Sv[3]);
            S = swap16_sum(S);
            S = swap32_sum(S);
            if (lenn1 == 0) zcap = c + __logf(S);
        }
        Bt0 = pack4(a0[0][0], a0[0][1], a0[0][2], a0[0][3]);
        Bt1 = pack4(a0[1][0], a0[1][1], a0[1][2], a0[1][3]);
        Bt2 = pack4(a0[2][0], a0[2][1], a0[2][2], a0[2][3]);
    }

    // float offset of this lane's granules in a slot: (col*13 + grp)*4;
    // X1/X2 at +16/+32 floats (granule step 4 = 64B)
    const int foff = col * 52 + grp * 4;
    const f32x4 zero4 = {0.f, 0.f, 0.f, 0.f};

#define XLOAD(dst, SLOT)                                                   \
        {                                                                  \
            const float* sp = reinterpret_cast<const float*>(              \
                ring + (SLOT) * SLOTB) + foff;                             \
            dst[0] = *reinterpret_cast<const f32x4*>(sp);                  \
            dst[1] = *reinterpret_cast<const f32x4*>(sp + 16);             \
            dst[2] = *reinterpret_cast<const f32x4*>(sp + 32);             \
        }

#define CPHASE(K_, SB)                                                       \
    {                                                                        \
        const int kc = (K_);                                                 \
        for (;;) {                            /* one b128 read = all flags */\
            i32x4 f = *(volatile i32x4*)prodCnt4;                            \
            if (f[0] >= kc + 1 && f[1] >= kc + 1 && f[2] >= kc + 1) break;   \
        }                                                                    \
        asm volatile("" ::: "memory");                                       \
        const int t0 = 1 + kc * PHASE;                                       \
        f32x4 Xq[PHASE + 2][3];                                              \
        XLOAD(Xq[0], ((SB) + 0) & (NSLOT - 1));                              \
        XLOAD(Xq[1], ((SB) + 1) & (NSLOT - 1));                              \
        _Pragma("unroll")                                                    \
        for (int s8 = 0; s8 < PHASE; ++s8) {                                 \
            if (s8 + 2 < PHASE)               /* depth-2 prefetch */         \
                XLOAD(Xq[s8 + 2], ((SB) + s8 + 2) & (NSLOT - 1));            \
            if (s8 == PHASE - 1) {                                           \
                /* all phase reads issued & (lgkm-waited) returned: flag */  \
                asm volatile("s_waitcnt lgkmcnt(0)" ::: "memory");           \
                if (lane == 0) *(volatile int*)&consCnt = kc + 1;            \
                asm volatile("" ::: "memory");                               \
            }                                                                \
            const int t = t0 + s8;            /* may exceed nsteps: ok */    \
            f32x4 D0 = mfma16(A[0][0], Bt0, zero4);                          \
            f32x4 D1 = mfma16(A[1][0], Bt0, zero4);                          \
            f32x4 D2 = mfma16(A[2][0], Bt0, zero4);                          \
            D0 = mfma16(A[0][1], Bt1, D0);                                   \
            D1 = mfma16(A[1][1], Bt1, D1);                                   \
            D2 = mfma16(A[2][1], Bt1, D2);                                   \
            D0 = mfma16(A[0][2], Bt2, D0);                                   \
            D1 = mfma16(A[1][2], Bt2, D1);                                   \
            D2 = mfma16(A[2][2], Bt2, D2);                                   \
            f32x4 Wa = D0 * Xq[s8][0];        /* pre-exp'd emissions */      \
            f32x4 Wb = D1 * Xq[s8][1];                                       \
            f32x4 Wc = D2 * Xq[s8][2];                                       \
            if (s8 == PHASE - 1) {            /* t = 8+8k: rescale */        \
                float mx = fmaxf(                                            \
                    fmaxf(fmaxf(fmaxf(Wa[0], Wa[1]), fmaxf(Wa[2], Wa[3])),   \
                          fmaxf(fmaxf(Wb[0], Wb[1]), fmaxf(Wb[2], Wb[3]))),  \
                    fmaxf(fmaxf(Wc[0], Wc[1]), fmaxf(Wc[2], Wc[3])));        \
                mx = swap16_max(mx);                                         \
                mx = swap32_max(mx);                                         \
                c += __logf(mx);                                             \
                float rm = __builtin_amdgcn_rcpf(mx);                        \
                Wa *= rm; Wb *= rm; Wc *= rm;                                \
            }                                                                \
            if (__ballot(t == lenn1)) {       /* rare capture */             \
                f32x4 Sv = Wa * EF[0] + Wb * EF[1] + Wc * EF[2];             \
                float S = (Sv[0] + Sv[1]) + (Sv[2] + Sv[3]);                 \
                S = swap16_sum(S);                                           \
                S = swap32_sum(S);                                           \
                if (t == lenn1) zcap = c + __logf(S);                        \
            }                                                                \
            Bt0 = pack4(Wa[0], Wa[1], Wa[2], Wa[3]);                         \
            Bt1 = pack4(Wb[0], Wb[1], Wb[2], Wb[3]);                         \
            Bt2 = pack4(Wc[0], Wc[1], Wc[2], Wc[3]);                         \
        }                                                                    \
    }

    for (int k0 = 0; k0 < nphase; k0 += 2) {
        CPHASE(k0, 1);                         // t0 % 16 == 1
        if (k0 + 1 < nphase) CPHASE(k0 + 1, 9); // t0 % 16 == 9
    }
#undef CPHASE
#undef XLOAD

    if (lane < GG) ws[seq] = zcap;   // 4 replicas agree; lanes 0..15 write
}

__global__ __launch_bounds__(512) void reduce_mean_kernel(
    const float* __restrict__ ws, float* __restrict__ out)
{
    __shared__ float sm[8];
    int tid = threadIdx.x;          // 512 threads = 8 waves
    float x = ws[tid] - ws[BB + tid];   // logZ_b - path_b
    x = wave_reduce_sum(x);
    if ((tid & 63) == 0) sm[tid >> 6] = x;
    __syncthreads();
    if (tid < 8) {
        float y = sm[tid];
        y += __shfl_xor(y, 1, 64);
        y += __shfl_xor(y, 2, 64);
        y += __shfl_xor(y, 4, 64);
        if (tid == 0) out[0] = y * (1.0f / 512.0f);
    }
}

extern "C" void kernel_launch(void* const* d_in, const int* in_sizes, int n_in,
                              void* d_out, int out_size, void* d_ws, size_t ws_size,
                              hipStream_t stream) {
    const float* emis    = (const float*)d_in[0];
    const int*   lengths = (const int*)  d_in[1];
    const int*   tags    = (const int*)  d_in[2];
    const float* prior   = (const float*)d_in[3];
    const float* trans   = (const float*)d_in[4];
    const float* finalT  = (const float*)d_in[5];

    float* ws  = (float*)d_ws;     // [0..511] logZ, [512..1023] path score
    float* out = (float*)d_out;

    crf_main_kernel<<<NGRP + BB, BLKT, 0, stream>>>(emis, lengths, tags, prior,
                                                    trans, finalT, ws);
    reduce_mean_kernel<<<1, 512, 0, stream>>>(ws, out);
}